// Round 4
// baseline (500.871 us; speedup 1.0000x reference)
//
#include <hip/hip_runtime.h>
#include <math.h>

// Problem constants
constexpr int B = 256;
constexpr int C = 512;
constexpr int N = 512;
constexpr int K = 256;   // = B
constexpr int WIN = 128; // n-window per block in k_main2

// ws layout (floats)
constexpr size_t OFF_CLIPNB = 0;                            // B*C bf16 = B*C/2 floats
constexpr size_t OFF_SGLOB  = OFF_CLIPNB + (size_t)B*C/2;   // B*K
constexpr size_t OFF_SSOFT  = OFF_SGLOB + (size_t)B*K;      // B*K
constexpr size_t OFF_SHARD  = OFF_SSOFT + (size_t)B*K;      // B*K
constexpr size_t OFF_PM     = OFF_SHARD + (size_t)B*K;      // 8*B*K  [b][p][k], p=win*2+ng
constexpr size_t OFF_PS     = OFF_PM    + (size_t)8*B*K;    // 8*B*K
constexpr size_t OFF_PG     = OFF_PS    + (size_t)8*B*K;    // 8*B*K
constexpr size_t OFF_S1     = OFF_PG    + (size_t)8*B*K;    // 2048*512 S1 partials
constexpr size_t OFF_GN     = OFF_S1    + (size_t)2048*512; // B
constexpr size_t OFF_MISC   = OFF_GN    + (size_t)B;        // 7

typedef __attribute__((ext_vector_type(8)))  short short8;
typedef __attribute__((ext_vector_type(16))) float f32x16;

__device__ __forceinline__ float wave_reduce_sum(float v) {
  #pragma unroll
  for (int off = 32; off > 0; off >>= 1) v += __shfl_xor(v, off, 64);
  return v;
}
__device__ __forceinline__ float wave_reduce_max(float v) {
  #pragma unroll
  for (int off = 32; off > 0; off >>= 1) v = fmaxf(v, __shfl_xor(v, off, 64));
  return v;
}
__device__ __forceinline__ unsigned int bf16_rne(float x) {
  unsigned int u = __builtin_bit_cast(unsigned int, x);
  return (u + 0x7FFFu + ((u >> 16) & 1u)) >> 16;
}
__device__ __forceinline__ unsigned int pk_bf16(float x, float y) {
  return bf16_rne(x) | (bf16_rne(y) << 16);
}

// ---------------- K0: scale + zero focal accumulators ----------------
__global__ void k_misc(const float* __restrict__ ls, float* __restrict__ misc) {
  int t = threadIdx.x;
  if (t == 0) misc[0] = fminf(fmaxf(expf(ls[0]), 0.01f), 100.0f);
  if (t >= 1 && t < 7) misc[t] = 0.0f;
}

// ---------------- K1: l2-normalize clip rows -> bf16 ----------------
__global__ __launch_bounds__(256) void k_rownorm(const float* __restrict__ src,
                                                 unsigned short* __restrict__ dst_bf) {
  int b = blockIdx.x, t = threadIdx.x;
  float x0 = src[(size_t)b * C + t];
  float x1 = src[(size_t)b * C + t + 256];
  __shared__ float red[4];
  float w = wave_reduce_sum(x0 * x0 + x1 * x1);
  if ((t & 63) == 0) red[t >> 6] = w;
  __syncthreads();
  float tot = red[0] + red[1] + red[2] + red[3];
  float r = 1.0f / fmaxf(sqrtf(tot), 1e-12f);
  dst_bf[(size_t)b * C + t] = (unsigned short)bf16_rne(x0 * r);
  dst_bf[(size_t)b * C + t + 256] = (unsigned short)bf16_rne(x1 * r);
}

// ---------------- K2: one-pass fused main kernel ----------------
// grid 1024: bw -> b = bw>>2, win = bw&3 (n in [win*128, win*128+128))
// 512 threads = 8 waves: wave w -> kq = w&3 (kt in {kq, kq+4}), ng = w>>2
// (nt in {2ng, 2ng+1}).  Whole 128n x 512c x-window staged once as bf16 in
// 128 KB LDS (rot(n) = 4(n&3)+16*n2+8*n3 within 32-dword blocks: b128 frag
// reads hit every bank exactly 8x = optimal; write conflicts hide under HBM).
// Fused outputs per block: PM/PS (softmax partials; hard-max == PM), PG
// (global-branch partial dot), S1 (gnorm partial matvec).
__global__ __launch_bounds__(512, 2) void k_main2(
    const float* __restrict__ yolo,
    const unsigned short* __restrict__ clipnb,
    const float* __restrict__ misc,
    float* __restrict__ PM, float* __restrict__ PS, float* __restrict__ PG,
    float* __restrict__ S1p) {
  int bw = blockIdx.x;
  int b = bw >> 2, win = bw & 3;
  int t = threadIdx.x;
  int w = t >> 6, lane = t & 63;
  int half = lane >> 5, nl = lane & 31;
  int kq = w & 3, ng = w >> 2;

  __shared__ unsigned int xl[WIN * 256];   // 128 KB [n][cpair, rotated]
  __shared__ float ssqb[16 * WIN];         // 8 KB
  __shared__ float invt[WIN];

  const float scale = misc[0];
  const float* ybase = yolo + (size_t)b * C * N + win * WIN;

  // ---- staging: 512c x 128n fp32 -> bf16 transpose + ssq ----
  {
    int nf = t & 31, cq = t >> 5;
    int row = 4 * nf;
    unsigned rw = 16u * (nf & 1) + 8u * ((nf >> 1) & 1);
    float4 ssq4 = {0.f, 0.f, 0.f, 0.f};
    #pragma unroll 4
    for (int p = 0; p < 16; p++) {
      int cp = cq + 16 * p;               // c-pair 0..255
      const float* pa = ybase + (size_t)(2 * cp) * N + 4 * nf;
      float4 a  = *(const float4*)pa;
      float4 bb = *(const float4*)(pa + N);
      ssq4.x += a.x * a.x + bb.x * bb.x;
      ssq4.y += a.y * a.y + bb.y * bb.y;
      ssq4.z += a.z * a.z + bb.z * bb.z;
      ssq4.w += a.w * a.w + bb.w * bb.w;
      int bhi = cp & ~31;
      xl[(row + 0) * 256 + bhi + (int)(((unsigned)cp + rw +  0u) & 31u)] = pk_bf16(a.x, bb.x);
      xl[(row + 1) * 256 + bhi + (int)(((unsigned)cp + rw +  4u) & 31u)] = pk_bf16(a.y, bb.y);
      xl[(row + 2) * 256 + bhi + (int)(((unsigned)cp + rw +  8u) & 31u)] = pk_bf16(a.z, bb.z);
      xl[(row + 3) * 256 + bhi + (int)(((unsigned)cp + rw + 12u) & 31u)] = pk_bf16(a.w, bb.w);
    }
    ssqb[cq * WIN + row + 0] = ssq4.x;
    ssqb[cq * WIN + row + 1] = ssq4.y;
    ssqb[cq * WIN + row + 2] = ssq4.z;
    ssqb[cq * WIN + row + 3] = ssq4.w;
  }
  __syncthreads();
  if (t < WIN) {
    float s = 0.f;
    #pragma unroll
    for (int g = 0; g < 16; g++) s += ssqb[g * WIN + t];
    invt[t] = 1.0f / fmaxf(sqrtf(s), 1e-12f);
  }
  __syncthreads();

  // ---- MFMA phase: 32x32x16, 4 tiles/wave, all 512 c in one sweep ----
  int kt0 = kq, kt1 = kq + 4;
  int nt0 = 2 * ng, nt1 = 2 * ng + 1;
  const unsigned short* a0p = clipnb + (size_t)(32 * kt0 + nl) * C + 8 * half;
  const unsigned short* a1p = clipnb + (size_t)(32 * kt1 + nl) * C + 8 * half;
  int brow0 = (32 * nt0 + nl) * 256;
  int brow1 = (32 * nt1 + nl) * 256;
  unsigned rotr = 4u * ((unsigned)(nl & 3) + 4u * ((nl >> 2) & 1) + 2u * ((nl >> 3) & 1));

  f32x16 acc00, acc01, acc10, acc11;
  #pragma unroll
  for (int r = 0; r < 16; r++) { acc00[r] = 0.f; acc01[r] = 0.f; acc10[r] = 0.f; acc11[r] = 0.f; }

  #pragma unroll 4
  for (int step = 0; step < 32; step++) {
    union { uint4 u; short8 v; } A0, A1, B0, B1;
    A0.u = *(const uint4*)(a0p + 16 * step);
    A1.u = *(const uint4*)(a1p + 16 * step);
    int pos = 32 * (step >> 2) +
              (int)(((unsigned)(8 * (step & 3) + 4 * half) + rotr) & 31u);
    B0.u = *(const uint4*)&xl[brow0 + pos];
    B1.u = *(const uint4*)&xl[brow1 + pos];
    acc00 = __builtin_amdgcn_mfma_f32_32x32x16_bf16(A0.v, B0.v, acc00, 0, 0, 0);
    acc01 = __builtin_amdgcn_mfma_f32_32x32x16_bf16(A0.v, B1.v, acc01, 0, 0, 0);
    acc10 = __builtin_amdgcn_mfma_f32_32x32x16_bf16(A1.v, B0.v, acc10, 0, 0, 0);
    acc11 = __builtin_amdgcn_mfma_f32_32x32x16_bf16(A1.v, B1.v, acc11, 0, 0, 0);
  }

  // ---- epilogue: fold inv, reduce over this wave's 64 n per k ----
  float ivr0 = invt[32 * nt0 + nl];
  float ivr1 = invt[32 * nt1 + nl];
  size_t pb = ((size_t)b * 8 + win * 2 + ng) * 256;
  #pragma unroll
  for (int tk = 0; tk < 2; tk++) {
    int kbase = 32 * (tk ? kt1 : kt0);
    #pragma unroll
    for (int reg = 0; reg < 16; reg++) {
      float u0 = (tk ? acc10[reg] : acc00[reg]) * ivr0;
      float u1 = (tk ? acc11[reg] : acc01[reg]) * ivr1;
      float v0 = u0 * scale, v1 = u1 * scale;
      float M = fmaxf(v0, v1);
      float G = u0 + u1;
      #pragma unroll
      for (int o = 1; o < 32; o <<= 1) M = fmaxf(M, __shfl_xor(M, o, 64));
      float e = __expf(v0 - M) + __expf(v1 - M);
      #pragma unroll
      for (int o = 1; o < 32; o <<= 1) {
        e += __shfl_xor(e, o, 64);
        G += __shfl_xor(G, o, 64);
      }
      if (nl == 0) {
        int k = kbase + (reg & 3) + 8 * (reg >> 2) + 4 * half;
        PM[pb + k] = M;
        PS[pb + k] = e;
        PG[pb + k] = G;
      }
    }
  }

  // ---- S1 partial (gnorm matvec): S1[c] = sum_n xbf[n][c]*inv[n] ----
  {
    int cp2 = t >> 1, sub = t & 1;
    int qhi = cp2 & ~31, qlo = cp2 & 31;
    float s0 = 0.f, s1 = 0.f;
    #pragma unroll 16
    for (int i = 0; i < 64; i++) {
      int n = 64 * sub + i;
      unsigned rt = 4u * (unsigned)(i & 3) + 16u * ((i >> 2) & 1) + 8u * ((i >> 3) & 1);
      unsigned dw = xl[n * 256 + qhi + (int)(((unsigned)qlo + rt) & 31u)];
      float iv = invt[n];
      float xlo = __builtin_bit_cast(float, dw << 16);
      float xhi = __builtin_bit_cast(float, dw & 0xffff0000u);
      s0 = fmaf(xlo, iv, s0);
      s1 = fmaf(xhi, iv, s1);
    }
    size_t o = ((size_t)bw * 2 + sub) * 512 + 2 * cp2;
    S1p[o] = s0;
    S1p[o + 1] = s1;
  }
}

// ---------------- K3: gn[b] = max(||sum S1||/N, eps) ----------------
__global__ __launch_bounds__(256) void k_gn2(const float* __restrict__ S1p,
                                             float* __restrict__ gn) {
  int b = blockIdx.x, t = threadIdx.x;
  float tot = 0.f;
  #pragma unroll
  for (int cc = 0; cc < 2; cc++) {
    int c = t + 256 * cc;
    float s = 0.f;
    #pragma unroll
    for (int wn = 0; wn < 4; wn++)
      #pragma unroll
      for (int sub = 0; sub < 2; sub++)
        s += S1p[(((size_t)(b * 4 + wn)) * 2 + sub) * 512 + c];
    tot += s * s;
  }
  __shared__ float red[4];
  float wsum = wave_reduce_sum(tot);
  if ((t & 63) == 0) red[t >> 6] = wsum;
  __syncthreads();
  if (t == 0) {
    float s = red[0] + red[1] + red[2] + red[3];
    gn[b] = fmaxf(sqrtf(s) * (1.0f / (float)N), 1e-12f);
  }
}

// ---------------- K4: Sglob from PG + gn ----------------
__global__ __launch_bounds__(256) void k_sglob(const float* __restrict__ PG,
                                               const float* __restrict__ gn,
                                               const float* __restrict__ misc,
                                               float* __restrict__ Sglob) {
  int i = blockIdx.x, k = threadIdx.x;
  float v = 0.f;
  #pragma unroll
  for (int p = 0; p < 8; p++) v += PG[((size_t)i * 8 + p) * 256 + k];
  Sglob[(size_t)i * K + k] = misc[0] * v * (1.0f / (float)N) / gn[i];
}

// ---------------- K5: merge 8 partials -> Ssoft, Shard ----------------
__global__ __launch_bounds__(256) void k_merge(const float* __restrict__ PM,
                                               const float* __restrict__ PS,
                                               float* __restrict__ Ssoft,
                                               float* __restrict__ Shard) {
  int b = blockIdx.x, k = threadIdx.x;
  float M = -1e30f;
  #pragma unroll
  for (int p = 0; p < 8; p++) M = fmaxf(M, PM[((size_t)b * 8 + p) * 256 + k]);
  float S = 0.f;
  #pragma unroll
  for (int p = 0; p < 8; p++) {
    size_t o = ((size_t)b * 8 + p) * 256 + k;
    S += PS[o] * __expf(PM[o] - M);
  }
  Ssoft[(size_t)b * K + k] = M + __logf(S);
  Shard[(size_t)b * K + k] = M;
}

// ---------------- K6: focal CE per row/col of each 256x256 matrix ----------------
__global__ __launch_bounds__(256) void k_focal(const float* __restrict__ Sglob,
                                               const float* __restrict__ Ssoft,
                                               const float* __restrict__ Shard,
                                               float* __restrict__ misc) {
  int job = blockIdx.y;   // 0..5: {glob,globT,soft,softT,hard,hardT}
  int i = blockIdx.x;
  int t = threadIdx.x;
  const float* M = job < 2 ? Sglob : (job < 4 ? Ssoft : Shard);
  float v = (job & 1) ? M[(size_t)t * K + i] : M[(size_t)i * K + t];
  __shared__ float red[4];
  float mx = wave_reduce_max(v);
  if ((t & 63) == 0) red[t >> 6] = mx;
  __syncthreads();
  mx = fmaxf(fmaxf(red[0], red[1]), fmaxf(red[2], red[3]));
  __syncthreads();
  float sv = wave_reduce_sum(v);
  if ((t & 63) == 0) red[t >> 6] = sv;
  __syncthreads();
  float sumv = red[0] + red[1] + red[2] + red[3];
  __syncthreads();
  float se = wave_reduce_sum(expf(v - mx));
  if ((t & 63) == 0) red[t >> 6] = se;
  __syncthreads();
  if (t == 0) {
    float sumexp = red[0] + red[1] + red[2] + red[3];
    float logZ = mx + logf(sumexp);
    float diag = M[(size_t)i * K + i];
    float nll = logZ - diag;                      // -log_p[label]
    float smooth = logZ - sumv * (1.0f / 256.0f); // -mean(log_p)
    float ce = 0.75f * nll + 0.25f * smooth;
    float pt = expf(-ce);
    float fo = (1.0f - pt) * (1.0f - pt) * ce;
    atomicAdd(&misc[1 + job], fo);
  }
}

// ---------------- K7: combine ----------------
__global__ void k_finish(const float* __restrict__ misc, float* __restrict__ out) {
  float lg = misc[1] + misc[2];
  float ls = misc[3] + misc[4];
  float lh = misc[5] + misc[6];
  out[0] = (0.2f * lg + 0.3f * ls + 0.5f * lh) * 0.5f * (1.0f / 256.0f);
}

extern "C" void kernel_launch(void* const* d_in, const int* in_sizes, int n_in,
                              void* d_out, int out_size, void* d_ws, size_t ws_size,
                              hipStream_t stream) {
  const float* yolo = (const float*)d_in[0];   // (B, C, N)
  const float* clip = (const float*)d_in[1];   // (B, C)
  const float* ls   = (const float*)d_in[2];   // (1,)
  float* out = (float*)d_out;
  float* ws = (float*)d_ws;
  unsigned short* clipnb = (unsigned short*)(ws + OFF_CLIPNB);
  float* Sglob = ws + OFF_SGLOB;
  float* Ssoft = ws + OFF_SSOFT;
  float* Shard = ws + OFF_SHARD;
  float* PM    = ws + OFF_PM;
  float* PS    = ws + OFF_PS;
  float* PG    = ws + OFF_PG;
  float* S1p   = ws + OFF_S1;
  float* gn    = ws + OFF_GN;
  float* misc  = ws + OFF_MISC;

  k_misc<<<1, 64, 0, stream>>>(ls, misc);
  k_rownorm<<<256, 256, 0, stream>>>(clip, clipnb);
  k_main2<<<1024, 512, 0, stream>>>(yolo, clipnb, misc, PM, PS, PG, S1p);
  k_gn2<<<256, 256, 0, stream>>>(S1p, gn);
  k_sglob<<<256, 256, 0, stream>>>(PG, gn, misc, Sglob);
  k_merge<<<256, 256, 0, stream>>>(PM, PS, Ssoft, Shard);
  k_focal<<<dim3(256, 6), 256, 0, stream>>>(Sglob, Ssoft, Shard, misc);
  k_finish<<<1, 1, 0, stream>>>(misc, out);
}